// Round 13
// baseline (1395.982 us; speedup 1.0000x reference)
//
#include <hip/hip_runtime.h>
#include <hip/hip_fp16.h>
#include <math.h>

// Sizes fixed by the problem
#define NB    64      // batches
#define NPTS  1024    // points per batch
#define HD    512
#define CPAD  576     // 513 padded to 9*64
#define COVE  ((size_t)NB*CPAD*CPAD)

typedef __attribute__((ext_vector_type(4))) float v4f;
typedef __attribute__((ext_vector_type(8))) short v8s;
typedef __attribute__((ext_vector_type(8))) _Float16 v8h;

// sin for tiny args (|z| << 1 by SIREN init): degree-7 Taylor
__device__ __forceinline__ float sin_poly(float z){
  float t = z*z;
  float p = fmaf(t, -1.9841270e-4f, 8.3333333e-3f);
  p = fmaf(t, p, -0.16666667f);
  p = fmaf(t, p, 1.0f);
  return z*p;
}

// split fp32 -> (hi, lo) fp16 pair; a ~= hi + lo to ~2^-23 rel
__device__ __forceinline__ ushort2 split_f16(float a){
  _Float16 h = (_Float16)a;
  float hf = (float)h;
  _Float16 l = (_Float16)(a - hf);
  unsigned short uh, ul;
  __builtin_memcpy(&uh, &h, 2);
  __builtin_memcpy(&ul, &l, 2);
  ushort2 r; r.x = uh; r.y = ul;
  return r;
}

__device__ __forceinline__ unsigned short f16b(float a){
  _Float16 h = (_Float16)a;
  unsigned short uh; __builtin_memcpy(&uh, &h, 2);
  return uh;
}

__device__ __forceinline__ float f16r(float a){   // round fp32 -> fp16 -> fp32
  return (float)(_Float16)a;
}

// ---------------- weight prep: W[k][n] fp32 -> single fp16 plane laid out [n][k] -------
__global__ __launch_bounds__(256)
void prep_k(const float* __restrict__ W1, const float* __restrict__ W2,
            const float* __restrict__ Wr, unsigned short* __restrict__ wf)
{
  int idx = blockIdx.x*256 + threadIdx.x;
  int mat = idx >> 18;
  int rem = idx & 0x3ffff;
  int k = rem >> 9, n = rem & 511;
  const float* W = (mat==0) ? W1 : ((mat==1) ? W2 : Wr);
  wf[(size_t)mat*262144 + (size_t)n*512 + k] = f16b(W[(size_t)k*512 + n]);
}

// ---------------- A-operand producer: fp16 plane (AMODE=0) or fused H0 (AMODE=1) -------
template<int AMODE>
__device__ __forceinline__ void load_a(const unsigned short* __restrict__ Ap,
                                       size_t ga0, size_t ga1, int K0,
                                       const float* __restrict__ w0,
                                       const float* __restrict__ b0, int sq,
                                       float xv0, float xv1,
                                       v8s& pa0, v8s& pa1)
{
  if (AMODE == 0){
    pa0 = *(const v8s*)(Ap + ga0 + K0); pa1 = *(const v8s*)(Ap + ga1 + K0);
  } else {
    const float* wp = w0 + K0 + sq*8;
    const float* bp = b0 + K0 + sq*8;
    float4 wva = *(const float4*)wp, wvb = *(const float4*)(wp+4);
    float4 bva = *(const float4*)bp, bvb = *(const float4*)(bp+4);
    float w8[8] = {wva.x,wva.y,wva.z,wva.w,wvb.x,wvb.y,wvb.z,wvb.w};
    float b8[8] = {bva.x,bva.y,bva.z,bva.w,bvb.x,bvb.y,bvb.z,bvb.w};
    #pragma unroll
    for (int i=0;i<8;++i){
      pa0[i] = (short)f16b(__sinf(30.f*fmaf(xv0, w8[i], b8[i])));
      pa1[i] = (short)f16b(__sinf(30.f*fmaf(xv1, w8[i], b8[i])));
    }
  }
}

// ---------------- LDS-staged single-pass fp16 MFMA GEMM ---------------------------------
// 256 thr = 4 waves (2x2), tile 128x128, BK=32, 16 MFMA + 8 ds_read_b128 per k-step.
// TRANS=0 -> single fp16 plane out (EPI=1 sin). TRANS=1 -> crT fp16 hi/lo [lb][512][1024].
// TRANS=2 -> fused predict: atomicAdd(ydot[row], sum_col sin(acc+bias)*vv[b][col]).
template<int EPI, int TRANS, int AMODE>
__global__ __launch_bounds__(256)
void gemm_ld(const unsigned short* __restrict__ Ap,
             const float* __restrict__ xsrc, const float* __restrict__ w0,
             const float* __restrict__ b0,
             const unsigned short* __restrict__ Bw,
             const float* __restrict__ bias,
             unsigned short* __restrict__ Chi, unsigned short* __restrict__ Clo,
             const float* __restrict__ vvp, float* __restrict__ ydot, int rowBase)
{
  __shared__ unsigned short Ah[128*40], Bh[128*40];
  const int tid  = threadIdx.x;
  const int lane = tid & 63, wave = tid >> 6;
  const int wm = wave & 1, wn = wave >> 1;
  const int m0 = blockIdx.x*128, n0 = blockIdx.y*128;
  const int q = lane >> 4, ln16 = lane & 15;
  const int sr = tid >> 2, sq = tid & 3;

  const size_t ga0 = (size_t)(m0 + sr)*512 + sq*8;
  const size_t ga1 = ga0 + (size_t)64*512;
  const size_t gb0 = (size_t)(n0 + sr)*512 + sq*8;
  const size_t gb1 = gb0 + (size_t)64*512;

  float xv0 = 0.f, xv1 = 0.f;
  if (AMODE == 1){ xv0 = xsrc[m0 + sr]; xv1 = xsrc[m0 + sr + 64]; }

  v8s pa0, pa1, pb0, pb1;
#define BLOAD(K0) do { \
    pb0 = *(const v8s*)(Bw + gb0 + (K0)); pb1 = *(const v8s*)(Bw + gb1 + (K0)); \
  } while(0)
#define STASH() do { \
    *(v8s*)(Ah + sr*40 + sq*8) = pa0; *(v8s*)(Ah + (sr+64)*40 + sq*8) = pa1; \
    *(v8s*)(Bh + sr*40 + sq*8) = pb0; *(v8s*)(Bh + (sr+64)*40 + sq*8) = pb1; \
  } while(0)

  v4f acc[4][4];
  #pragma unroll
  for (int a=0;a<4;++a)
    #pragma unroll
    for (int b=0;b<4;++b) acc[a][b] = (v4f)(0.0f);

  load_a<AMODE>(Ap, ga0, ga1, 0, w0, b0, sq, xv0, xv1, pa0, pa1);
  BLOAD(0);
  for (int ks=0; ks<16; ++ks){
    STASH();
    __syncthreads();
    if (ks < 15){
      const int k1 = (ks+1)*32;
      load_a<AMODE>(Ap, ga0, ga1, k1, w0, b0, sq, xv0, xv1, pa0, pa1);
      BLOAD(k1);
    }
    v8h bhf[4];
    #pragma unroll
    for (int nt=0; nt<4; ++nt){
      const int nrow = wn*64 + nt*16 + ln16;
      bhf[nt] = *(const v8h*)(Bh + nrow*40 + q*8);
    }
    #pragma unroll
    for (int mt=0; mt<4; ++mt){
      const int mrow = wm*64 + mt*16 + ln16;
      v8h ah = *(const v8h*)(Ah + mrow*40 + q*8);
      #pragma unroll
      for (int nt=0; nt<4; ++nt)
        acc[mt][nt] = __builtin_amdgcn_mfma_f32_16x16x32_f16(ah, bhf[nt], acc[mt][nt], 0,0,0);
    }
    __syncthreads();
  }
#undef BLOAD
#undef STASH

  if (TRANS == 0){
    #pragma unroll
    for (int nt=0;nt<4;++nt){
      const int col = n0 + wn*64 + nt*16 + ln16;
      const float bl_ = bias[col];
      #pragma unroll
      for (int mt=0;mt<4;++mt){
        const int row0 = m0 + wm*64 + mt*16 + q*4;
        #pragma unroll
        for (int r=0;r<4;++r){
          float v = acc[mt][nt][r] + bl_;
          if (EPI == 1) v = sin_poly(v);
          Chi[(size_t)(row0+r)*512 + col] = f16b(v);
        }
      }
    }
  } else if (TRANS == 1){
    const int lb = m0 >> 10;   // 128-row tile lies within one batch
    #pragma unroll
    for (int nt=0;nt<4;++nt){
      const int col = n0 + wn*64 + nt*16 + ln16;
      const float bl_ = bias[col];
      #pragma unroll
      for (int mt=0;mt<4;++mt){
        const int row0 = m0 + wm*64 + mt*16 + q*4;
        const int nb = row0 & 1023;
        ushort4 h,l; ushort2 s;
        s=split_f16(acc[mt][nt][0]+bl_); h.x=s.x; l.x=s.y;
        s=split_f16(acc[mt][nt][1]+bl_); h.y=s.x; l.y=s.y;
        s=split_f16(acc[mt][nt][2]+bl_); h.z=s.x; l.z=s.y;
        s=split_f16(acc[mt][nt][3]+bl_); h.w=s.x; l.w=s.y;
        size_t o = ((size_t)lb*512 + col)*1024 + nb;
        *(ushort4*)(Chi + o) = h;
        *(ushort4*)(Clo + o) = l;
      }
    }
  } else {
    const int b = (rowBase + m0) >> 10;
    const float* vb = vvp + (size_t)b*512;
    float vcol[4];
    float bl_[4];
    #pragma unroll
    for (int nt=0;nt<4;++nt){
      const int col = n0 + wn*64 + nt*16 + ln16;
      vcol[nt] = vb[col];
      bl_[nt] = bias[col];
    }
    #pragma unroll
    for (int mt=0;mt<4;++mt){
      #pragma unroll
      for (int r=0;r<4;++r){
        float part = 0.f;
        #pragma unroll
        for (int nt=0;nt<4;++nt)
          part = fmaf(sin_poly(acc[mt][nt][r] + bl_[nt]), vcol[nt], part);
        #pragma unroll
        for (int off=1; off<16; off<<=1) part += __shfl_xor(part, off, 64);
        if (ln16 == 0){
          const int row = m0 + wm*64 + mt*16 + q*4 + r;
          atomicAdd(&ydot[rowBase + row], part);
        }
      }
    }
  }
}

// ---------------- ext-feature row loader: f<512 -> crT planes; 512 -> 1; 513 -> yc -----
__device__ __forceinline__ void ld_ext_row(const unsigned short* __restrict__ h,
                                           const unsigned short* __restrict__ l,
                                           const float* __restrict__ ycn,
                                           int f, int nofs, v8s& oh, v8s& ol)
{
  if (f < 512){
    oh = *(const v8s*)(h + (size_t)f*1024 + nofs);
    ol = *(const v8s*)(l + (size_t)f*1024 + nofs);
  } else if (f == 512){
    #pragma unroll
    for (int j=0;j<8;++j){ oh[j] = (short)0x3C00; ol[j] = 0; }   // fp16 1.0
  } else if (f == 513){
    #pragma unroll
    for (int j=0;j<8;++j){
      ushort2 s = split_f16(ycn[nofs+j]);
      oh[j] = (short)s.x; ol[j] = (short)s.y;
    }
  } else {
    #pragma unroll
    for (int j=0;j<8;++j){ oh[j] = 0; ol[j] = 0; }
  }
}

// ---------------- cov: LDS-staged fp16 3-pass Gram of [cr|1|yc|0] over 1024 points -----
// Row 513 of the Gram = xty^T; after Cholesky, L[513][0:513] = La^{-1} xty = z (bordered).
__global__ __launch_bounds__(256)
void cov_ld(const unsigned short* __restrict__ CThi, const unsigned short* __restrict__ CTlo,
            const float* __restrict__ ycb,
            const float* __restrict__ lnv, float* __restrict__ cov, int bStart)
{
  int t = blockIdx.x;
  int ti = 0;
  while ((ti+1)*(ti+2)/2 <= t) ++ti;
  int tj = t - ti*(ti+1)/2;
  const int i0 = ti*128, j0 = tj*128;
  const int lb = blockIdx.y;
  const int b  = bStart + lb;
  const unsigned short* srch = CThi + (size_t)lb*512*1024;
  const unsigned short* srcl = CTlo + (size_t)lb*512*1024;
  const float* ycn = ycb + (size_t)b*NPTS;
  float* covb = cov + (size_t)b*CPAD*CPAD;
  const float noise = expf(lnv[0]);
  const bool diag = (i0 == j0);

  __shared__ unsigned short Ah[128*40], Al[128*40], Bh2[128*40], Bl2[128*40];
  const int tid = threadIdx.x;
  const int lane = tid & 63, wave = tid >> 6;
  const int wm = wave & 1, wn = wave >> 1;
  const int q = lane >> 4, ln16 = lane & 15;
  const int sr = tid >> 2, sq = tid & 3;

  const int fA0 = i0 + sr, fA1 = i0 + sr + 64;
  const int fB0 = j0 + sr, fB1 = j0 + sr + 64;

  v8s pah0, pah1, pal0, pal1, pbh0, pbh1, pbl0, pbl1;

  v4f acc[4][4];
  #pragma unroll
  for (int a=0;a<4;++a)
    #pragma unroll
    for (int c=0;c<4;++c) acc[a][c] = (v4f)(0.0f);

  ld_ext_row(srch, srcl, ycn, fA0, sq*8, pah0, pal0);
  ld_ext_row(srch, srcl, ycn, fA1, sq*8, pah1, pal1);
  if (!diag){
    ld_ext_row(srch, srcl, ycn, fB0, sq*8, pbh0, pbl0);
    ld_ext_row(srch, srcl, ycn, fB1, sq*8, pbh1, pbl1);
  }
  for (int ks=0; ks<32; ++ks){
    *(v8s*)(Ah + sr*40 + sq*8) = pah0; *(v8s*)(Ah + (sr+64)*40 + sq*8) = pah1;
    *(v8s*)(Al + sr*40 + sq*8) = pal0; *(v8s*)(Al + (sr+64)*40 + sq*8) = pal1;
    if (!diag){
      *(v8s*)(Bh2 + sr*40 + sq*8) = pbh0; *(v8s*)(Bh2 + (sr+64)*40 + sq*8) = pbh1;
      *(v8s*)(Bl2 + sr*40 + sq*8) = pbl0; *(v8s*)(Bl2 + (sr+64)*40 + sq*8) = pbl1;
    }
    __syncthreads();
    if (ks < 31){
      const int n1 = (ks+1)*32 + sq*8;
      ld_ext_row(srch, srcl, ycn, fA0, n1, pah0, pal0);
      ld_ext_row(srch, srcl, ycn, fA1, n1, pah1, pal1);
      if (!diag){
        ld_ext_row(srch, srcl, ycn, fB0, n1, pbh0, pbl0);
        ld_ext_row(srch, srcl, ycn, fB1, n1, pbh1, pbl1);
      }
    }
    const unsigned short* BhP = diag ? Ah : Bh2;
    const unsigned short* BlP = diag ? Al : Bl2;
    v8h bhf[4], blf[4];
    #pragma unroll
    for (int nt=0; nt<4; ++nt){
      const int nrow = wn*64 + nt*16 + ln16;
      bhf[nt] = *(const v8h*)(BhP + nrow*40 + q*8);
      blf[nt] = *(const v8h*)(BlP + nrow*40 + q*8);
    }
    #pragma unroll
    for (int mt=0; mt<4; ++mt){
      const int mrow = wm*64 + mt*16 + ln16;
      v8h ah = *(const v8h*)(Ah + mrow*40 + q*8);
      v8h al = *(const v8h*)(Al + mrow*40 + q*8);
      #pragma unroll
      for (int nt=0; nt<4; ++nt){
        acc[mt][nt] = __builtin_amdgcn_mfma_f32_16x16x32_f16(ah, bhf[nt], acc[mt][nt], 0,0,0);
        acc[mt][nt] = __builtin_amdgcn_mfma_f32_16x16x32_f16(ah, blf[nt], acc[mt][nt], 0,0,0);
        acc[mt][nt] = __builtin_amdgcn_mfma_f32_16x16x32_f16(al, bhf[nt], acc[mt][nt], 0,0,0);
      }
    }
    __syncthreads();
  }
  #pragma unroll
  for (int nt=0;nt<4;++nt){
    const int gj = j0 + wn*64 + nt*16 + ln16;
    #pragma unroll
    for (int mt=0;mt<4;++mt){
      const int gi0 = i0 + wm*64 + mt*16 + q*4;
      #pragma unroll
      for (int r=0;r<4;++r){
        const int gi = gi0 + r;
        if (gj <= gi && gi < CPAD && gj < CPAD){
          float v = acc[mt][nt][r];
          if (gi == gj) v += (gi < 513) ? noise : 1.0f;
          covb[(size_t)gi*CPAD + gj] = v;
        }
      }
    }
  }
}

// ---------------- Cholesky trsm: FIRST=1 factors raw diag (k=0, writes slot 0); --------
// FIRST=0 loads pre-factored diag from dchol slot k (written by trail(k-1) tile 0).
template<int FIRST>
__global__ __launch_bounds__(256)
void chol_trsm_k(float* __restrict__ cov, float* __restrict__ dchol, int k)
{
  float* Ab = cov + (size_t)blockIdx.x * CPAD * CPAD;
  const int o = k*64;
  const int row0 = o + 64 + blockIdx.y*128;
  const int nrows = min(128, CPAD - row0);
  __shared__ float Ds[64][65];
  __shared__ float As[128][65];
  __shared__ float invd[64];
  const int tid = threadIdx.x;

  if (FIRST){
    for (int idx=tid; idx<1024; idx+=256){
      int r = idx >> 4, c = (idx & 15)*4;
      float4 v = *(const float4*)(Ab + (size_t)(o+r)*CPAD + o + c);
      Ds[r][c]   = (c   <= r) ? v.x : 0.f;
      Ds[r][c+1] = (c+1 <= r) ? v.y : 0.f;
      Ds[r][c+2] = (c+2 <= r) ? v.z : 0.f;
      Ds[r][c+3] = (c+3 <= r) ? v.w : 0.f;
    }
  } else {
    const float* src = dchol + ((size_t)blockIdx.x*8 + k)*4096;
    for (int idx=tid; idx<4096; idx+=256)
      Ds[idx>>6][idx&63] = src[idx];
  }
  for (int idx=tid; idx<nrows*16; idx+=256){
    int r = idx >> 4, c = (idx & 15)*4;
    float4 v = *(const float4*)(Ab + (size_t)(row0+r)*CPAD + o + c);
    As[r][c]=v.x; As[r][c+1]=v.y; As[r][c+2]=v.z; As[r][c+3]=v.w;
  }
  __syncthreads();

  if (FIRST){
    for (int j=0; j<64; ++j){
      if (tid == 0) Ds[j][j] = sqrtf(Ds[j][j]);
      __syncthreads();
      float dj = Ds[j][j];
      if (tid > j && tid < 64) Ds[tid][j] /= dj;
      __syncthreads();
      {
        int i = j + 1 + (tid & 63);
        int g = tid >> 6;
        if (i < 64){
          float lij = Ds[i][j];
          for (int c = j+1+g; c <= i; c += 4)
            Ds[i][c] = fmaf(-lij, Ds[c][j], Ds[i][c]);
        }
      }
      __syncthreads();
    }
    if (blockIdx.y == 0){
      float* dst = dchol + ((size_t)blockIdx.x*8 + k)*4096;
      for (int idx=tid; idx<4096; idx+=256){
        int r = idx >> 6, c = idx & 63;
        dst[idx] = (c <= r) ? Ds[r][c] : 0.f;
      }
    }
  }
  if (tid < 64) invd[tid] = 1.0f / Ds[tid][tid];
  __syncthreads();

  if (tid < nrows){
    float x[64];
    #pragma unroll
    for (int c=0; c<64; ++c){
      float s = As[tid][c];
      #pragma unroll
      for (int j=0; j<c; ++j) s = fmaf(-x[j], Ds[c][j], s);
      x[c] = s * invd[c];
    }
    #pragma unroll
    for (int c=0; c<64; ++c) As[tid][c] = x[c];
  }
  __syncthreads();
  for (int idx=tid; idx<nrows*16; idx+=256){
    int r = idx >> 4, c = (idx & 15)*4;
    float4 v = make_float4(As[r][c], As[r][c+1], As[r][c+2], As[r][c+3]);
    *(float4*)(Ab + (size_t)(row0+r)*CPAD + o + c) = v;
  }
}

// ---------------- trailing rank-64 syrk (k=0..6); tile (0,0) also factors the next -----
// diag in LDS and writes dchol slot k+1 (fully updated: RMW'd value incl this panel).
__global__ __launch_bounds__(256)
void chol_trail_k(float* __restrict__ cov, float* __restrict__ dchol, int k)
{
  float* Ab = cov + (size_t)blockIdx.y * CPAD * CPAD;
  int t = blockIdx.x;
  int bi = 0;
  while ((bi+1)*(bi+2)/2 <= t) ++bi;
  int bj = t - bi*(bi+1)/2;
  const int o = k*64;
  const int s0 = o + 64;
  const int I = s0 + bi*64, J = s0 + bj*64;
  const bool isDiag0 = (t == 0);

  __shared__ float Pi[64*64];   // transposed [kk][i]
  __shared__ float Pj[64*64];
  __shared__ float Ds[64][65];
  const int tid = threadIdx.x;
  for (int idx = tid; idx < 1024; idx += 256){
    int r = idx >> 4, cq = idx & 15;
    float4 v = *(const float4*)(Ab + (size_t)(I+r)*CPAD + o + cq*4);
    Pi[(cq*4+0)*64 + r] = v.x; Pi[(cq*4+1)*64 + r] = v.y;
    Pi[(cq*4+2)*64 + r] = v.z; Pi[(cq*4+3)*64 + r] = v.w;
    float4 u = *(const float4*)(Ab + (size_t)(J+r)*CPAD + o + cq*4);
    Pj[(cq*4+0)*64 + r] = u.x; Pj[(cq*4+1)*64 + r] = u.y;
    Pj[(cq*4+2)*64 + r] = u.z; Pj[(cq*4+3)*64 + r] = u.w;
  }
  __syncthreads();
  const int tx = tid & 15, ty = tid >> 4;
  float acc[4][4];
  #pragma unroll
  for (int r=0;r<4;++r)
    #pragma unroll
    for (int c=0;c<4;++c) acc[r][c]=0.f;
  for (int kk=0; kk<64; ++kk){
    float4 a4 = *(const float4*)(Pi + kk*64 + tx*4);
    float4 b4 = *(const float4*)(Pj + kk*64 + ty*4);
    float av[4]={a4.x,a4.y,a4.z,a4.w}, bv[4]={b4.x,b4.y,b4.z,b4.w};
    #pragma unroll
    for (int r=0;r<4;++r)
      #pragma unroll
      for (int c=0;c<4;++c) acc[r][c] = fmaf(av[r], bv[c], acc[r][c]);
  }
  #pragma unroll
  for (int r=0;r<4;++r){
    int gi = I + tx*4 + r;
    #pragma unroll
    for (int c=0;c<4;++c){
      int gj = J + ty*4 + c;
      if (gj <= gi){
        size_t id = (size_t)gi*CPAD + gj;
        float nv = Ab[id] - acc[r][c];
        Ab[id] = nv;
        if (isDiag0) Ds[tx*4+r][ty*4+c] = nv;
      }
    }
  }
  if (isDiag0){
    __syncthreads();
    // factor the updated diag (lower) and persist to dchol slot k+1
    for (int j=0; j<64; ++j){
      if (tid == 0) Ds[j][j] = sqrtf(Ds[j][j]);
      __syncthreads();
      float dj = Ds[j][j];
      if (tid > j && tid < 64) Ds[tid][j] /= dj;
      __syncthreads();
      {
        int i = j + 1 + (tid & 63);
        int g = tid >> 6;
        if (i < 64){
          float lij = Ds[i][j];
          for (int c = j+1+g; c <= i; c += 4)
            Ds[i][c] = fmaf(-lij, Ds[c][j], Ds[i][c]);
        }
      }
      __syncthreads();
    }
    float* dst = dchol + ((size_t)blockIdx.y*8 + k + 1)*4096;
    for (int idx=tid; idx<4096; idx+=256){
      int r = idx >> 6, c = idx & 63;
      dst[idx] = (c <= r) ? Ds[r][c] : 0.f;
    }
  }
}

// ---------------- fused: trail(7) + diag-8 factor + backward solve + head fold ---------
// One block per batch, 512 thr. z = L[513][0:513] (bordered); z[512] = diag8 L[1][0].
// Head fold reads fp32 Wr rows with f16r (matches crT gemm's rounded weights).
__global__ __launch_bounds__(512)
void solve_all_k(float* __restrict__ cov, const float* __restrict__ dchol,
                 const float* __restrict__ Wr, const float* __restrict__ br,
                 float* __restrict__ vv, float* __restrict__ cvec)
{
  const int b = blockIdx.x;
  float* L = cov + (size_t)b*CPAD*CPAD;
  const float* dc = dchol + (size_t)b*8*4096;
  __shared__ float Ps[64][65];
  __shared__ float Ds[64][65];
  __shared__ float rhs[CPAD];
  __shared__ float invd[CPAD];
  __shared__ float red[512];
  const int tid = threadIdx.x, lane = tid & 63;

  // load trsm'd panel 7 (rows 512..575, cols 448..511) and raw diag8 (lower)
  for (int idx=tid; idx<1024; idx+=512){
    int r = idx >> 4, c = (idx & 15)*4;
    float4 v = *(const float4*)(L + (size_t)(512+r)*CPAD + 448 + c);
    Ps[r][c]=v.x; Ps[r][c+1]=v.y; Ps[r][c+2]=v.z; Ps[r][c+3]=v.w;
    float4 u = *(const float4*)(L + (size_t)(512+r)*CPAD + 512 + c);
    Ds[r][c]   = (c   <= r) ? u.x : 0.f;
    Ds[r][c+1] = (c+1 <= r) ? u.y : 0.f;
    Ds[r][c+2] = (c+2 <= r) ? u.z : 0.f;
    Ds[r][c+3] = (c+3 <= r) ? u.w : 0.f;
  }
  __syncthreads();
  // Ds -= Ps Ps^T (lower), 256-thread 4x4 micro
  if (tid < 256){
    const int tx = tid & 15, ty = tid >> 4;
    float acc[4][4];
    #pragma unroll
    for (int r=0;r<4;++r)
      #pragma unroll
      for (int c=0;c<4;++c) acc[r][c]=0.f;
    for (int kk=0; kk<64; ++kk){
      float av[4], bv[4];
      #pragma unroll
      for (int r=0;r<4;++r) av[r] = Ps[tx*4+r][kk];
      #pragma unroll
      for (int c=0;c<4;++c) bv[c] = Ps[ty*4+c][kk];
      #pragma unroll
      for (int r=0;r<4;++r)
        #pragma unroll
        for (int c=0;c<4;++c) acc[r][c] = fmaf(av[r], bv[c], acc[r][c]);
    }
    #pragma unroll
    for (int r=0;r<4;++r){
      int gi = tx*4 + r;
      #pragma unroll
      for (int c=0;c<4;++c){
        int gj = ty*4 + c;
        if (gj <= gi) Ds[gi][gj] -= acc[r][c];
      }
    }
  }
  __syncthreads();
  // factor diag8 in LDS
  for (int j=0; j<64; ++j){
    if (tid == 0) Ds[j][j] = sqrtf(Ds[j][j]);
    __syncthreads();
    float dj = Ds[j][j];
    if (tid > j && tid < 64) Ds[tid][j] /= dj;
    __syncthreads();
    {
      int i = j + 1 + (tid & 63);
      int g = tid >> 6;
      if (i < 64){
        float lij = Ds[i][j];
        for (int c = j+1+g; c <= i; c += 8)
          Ds[i][c] = fmaf(-lij, Ds[c][j], Ds[i][c]);
      }
    }
    __syncthreads();
  }

  // rhs = z; invd from dchol slots (i<512) and local Ds (i>=512)
  const float* zrow = L + (size_t)513*CPAD;
  for (int i=tid; i<CPAD; i+=512){
    rhs[i]  = (i < 512) ? zrow[i] : ((i == 512) ? Ds[1][0] : 0.f);
    invd[i] = (i < 512) ? 1.0f / dc[(size_t)(i>>6)*4096 + (size_t)(i&63)*65]
                        : 1.0f / Ds[i-512][i-512];
  }
  __syncthreads();

  // backward: L^T w = z  (k=8 uses Ds already in LDS)
  for (int k=8; k>=0; --k){
    const int o = k*64;
    if (k < 8){
      const float* src = dc + (size_t)k*4096;
      for (int idx=tid; idx<4096; idx+=512)
        Ds[idx>>6][idx&63] = src[idx];
      __syncthreads();
    }
    if (tid < 64){
      float acc = 0.f, myx = 0.f;
      for (int j=63; j>=0; --j){
        float t = (rhs[o+j] - acc) * invd[o+j];
        float xj = __shfl(t, j, 64);
        if (lane == j) myx = xj;
        if (lane < j) acc = fmaf(Ds[j][lane], xj, acc);
      }
      rhs[o+lane] = myx;
    }
    __syncthreads();
    if (tid < o){
      const int c = tid;
      float s0=0.f, s1=0.f, s2=0.f, s3=0.f;
      const float* lc = L + (size_t)o*CPAD + c;
      #pragma unroll 4
      for (int r=0; r<64; r+=4){
        s0 = fmaf(lc[(size_t)r*CPAD],     rhs[o+r],   s0);
        s1 = fmaf(lc[(size_t)(r+1)*CPAD], rhs[o+r+1], s1);
        s2 = fmaf(lc[(size_t)(r+2)*CPAD], rhs[o+r+2], s2);
        s3 = fmaf(lc[(size_t)(r+3)*CPAD], rhs[o+r+3], s3);
      }
      rhs[c] -= (s0+s1)+(s2+s3);
    }
    __syncthreads();
  }

  // head fold (R11 fold_k arithmetic): vv[j] = sum_r f16r(Wr[j][r]) * w[r]
  {
    const int j = tid;   // 512 threads, one output each
    const float* row = Wr + (size_t)j*512;
    float acc = 0.f;
    for (int r=0; r<512; r+=4){
      float4 w4 = *(const float4*)(row + r);
      acc = fmaf(f16r(w4.x), rhs[r],   acc);
      acc = fmaf(f16r(w4.y), rhs[r+1], acc);
      acc = fmaf(f16r(w4.z), rhs[r+2], acc);
      acc = fmaf(f16r(w4.w), rhs[r+3], acc);
    }
    vv[(size_t)b*512 + j] = acc;
    red[j] = br[j]*rhs[j];
  }
  __syncthreads();
  for (int s=256; s>0; s>>=1){ if (tid<s) red[tid]+=red[tid+s]; __syncthreads(); }
  if (tid == 0) cvec[b] = red[0] + rhs[512];
}

// ---------------- y stats + normalized yc ----------------------------------------------
__global__ __launch_bounds__(256)
void stats_k(const float* __restrict__ y, float* __restrict__ meanv,
             float* __restrict__ stdv, float* __restrict__ ycb)
{
  int b = blockIdx.x, tid = threadIdx.x;
  const float* yb = y + (size_t)b*NPTS;
  float4 v = *(const float4*)(yb + tid*4);
  float s  = v.x+v.y+v.z+v.w;
  float ss = v.x*v.x+v.y*v.y+v.z*v.z+v.w*v.w;
  #pragma unroll
  for (int off=32; off; off>>=1){ s += __shfl_down(s, off); ss += __shfl_down(ss, off); }
  __shared__ float rs[4], rss[4], bc[2];
  int wid = tid>>6, lane = tid&63;
  if (lane == 0){ rs[wid]=s; rss[wid]=ss; }
  __syncthreads();
  if (tid == 0){
    float S  = rs[0]+rs[1]+rs[2]+rs[3];
    float SS = rss[0]+rss[1]+rss[2]+rss[3];
    float mean = S * (1.0f/NPTS);
    float var  = (SS - S*S*(1.0f/NPTS)) * (1.0f/(NPTS-1));
    float sd = sqrtf(var);
    meanv[b]=mean; stdv[b]=sd; bc[0]=mean; bc[1]=1.0f/sd;
  }
  __syncthreads();
  float mean=bc[0], inv=bc[1];
  float4 o;
  o.x=(v.x-mean)*inv; o.y=(v.y-mean)*inv; o.z=(v.z-mean)*inv; o.w=(v.w-mean)*inv;
  *(float4*)(ycb + (size_t)b*NPTS + tid*4) = o;
}

// ---------------- finalize: out = (ydot + c)*std + mean --------------------------------
__global__ __launch_bounds__(256)
void fin_k(const float* __restrict__ ydot, const float* __restrict__ cvec,
           const float* __restrict__ meanv, const float* __restrict__ stdv,
           float* __restrict__ out)
{
  int i = blockIdx.x*256 + threadIdx.x;
  int b = i >> 10;
  out[i] = fmaf(ydot[i] + cvec[b], stdv[b], meanv[b]);
}

// =======================================================================================
extern "C" void kernel_launch(void* const* d_in, const int* in_sizes, int n_in,
                              void* d_out, int out_size, void* d_ws, size_t ws_size,
                              hipStream_t stream)
{
  (void)in_sizes; (void)n_in; (void)out_size;
  const float* x_ctx = (const float*)d_in[0];
  const float* y_ctx = (const float*)d_in[1];
  const float* x_tgt = (const float*)d_in[2];
  const float* W0 = (const float*)d_in[3];
  const float* b0 = (const float*)d_in[4];
  const float* W1 = (const float*)d_in[5];
  const float* b1 = (const float*)d_in[6];
  const float* W2 = (const float*)d_in[7];
  const float* b2 = (const float*)d_in[8];
  const float* Wr = (const float*)d_in[9];
  const float* br = (const float*)d_in[10];
  const float* lnv = (const float*)d_in[11];
  float* out = (float*)d_out;
  float* ws = (float*)d_ws;

  // unchunked preferred; shrink if ws forces
  int CH = 65536;
  for (;;){
    size_t fl = COVE + 65536 + 192 + (size_t)64*512 + 65536
              + (size_t)64*8*4096 + 64;
    size_t sh = (size_t)3*262144 + (size_t)2*CH*512 + (size_t)2*(CH/1024)*512*1024;
    size_t need = fl*4 + sh*2;
    if (ws_size >= need || CH <= 1024) break;
    CH >>= 1;
  }
  const int nch = 65536 / CH;
  const int bpc = CH / NPTS;

  float* cov   = ws;
  float* ycb   = cov + COVE;
  float* meanv = ycb + 65536;
  float* stdv  = meanv + 64;
  float* cvec  = stdv + 64;
  float* vvb   = cvec + 64;
  float* ydot  = vvb + (size_t)64*512;
  float* dchol = ydot + 65536;
  unsigned short* wf   = (unsigned short*)(dchol + (size_t)64*8*4096);
  unsigned short* P0   = wf + (size_t)3*262144;
  unsigned short* P1   = P0 + (size_t)CH*512;
  unsigned short* CThi = P1 + (size_t)CH*512;
  unsigned short* CTlo = CThi + (size_t)bpc*512*1024;

  prep_k<<<3072, 256, 0, stream>>>(W1, W2, Wr, wf);
  stats_k<<<NB, 256, 0, stream>>>(y_ctx, meanv, stdv, ycb);

  // context: fused-H0 MLP -> crT -> per-batch ext Gram (xty = Gram row 513, in cov)
  for (int c=0; c<nch; ++c){
    const float* xc = x_ctx + (size_t)c*CH;
    dim3 g(CH/128, 4);
    gemm_ld<1,0,1><<<g, 256, 0, stream>>>(0, xc, W0, b0, wf, b1, P1, 0, 0, 0, 0);
    gemm_ld<1,0,0><<<g, 256, 0, stream>>>(P1, 0, 0, 0, wf+262144, b2, P0, 0, 0, 0, 0);
    gemm_ld<0,1,0><<<g, 256, 0, stream>>>(P0, 0, 0, 0, wf+524288, br, CThi, CTlo, 0, 0, 0);
    cov_ld<<<dim3(15, bpc), 256, 0, stream>>>(CThi, CTlo, ycb, lnv, cov, c*bpc);
  }

  // batched blocked Cholesky; trail tile(0,0) pre-factors next diag into dchol
  for (int k=0; k<8; ++k){
    const int cnt = CPAD - k*64 - 64;
    dim3 gt(NB, (cnt + 127)/128);
    if (k == 0) chol_trsm_k<1><<<gt, 256, 0, stream>>>(cov, dchol, k);
    else        chol_trsm_k<0><<<gt, 256, 0, stream>>>(cov, dchol, k);
    if (k < 7){
      const int tcnt = cnt >> 6;
      chol_trail_k<<<dim3(tcnt*(tcnt+1)/2, NB), 256, 0, stream>>>(cov, dchol, k);
    }
  }
  // trail(7) + diag-8 factor + backward solve + head fold, fused
  solve_all_k<<<NB, 512, 0, stream>>>(cov, dchol, Wr, br, vvb, cvec);

  // targets: fused-H0 MLP to H1 plane, then H2-GEMM fused with the folded dot
  hipMemsetAsync(ydot, 0, 65536*sizeof(float), stream);
  for (int c=0; c<nch; ++c){
    const float* xt = x_tgt + (size_t)c*CH;
    dim3 g(CH/128, 4);
    gemm_ld<1,0,1><<<g, 256, 0, stream>>>(0, xt, W0, b0, wf, b1, P1, 0, 0, 0, 0);
    gemm_ld<1,2,0><<<g, 256, 0, stream>>>(P1, 0, 0, 0, wf+262144, b2, 0, 0, vvb, ydot, c*CH);
  }
  fin_k<<<256, 256, 0, stream>>>(ydot, cvec, meanv, stdv, out);
}